// Round 8
// baseline (270.710 us; speedup 1.0000x reference)
//
#include <hip/hip_runtime.h>
#include <hip/hip_bf16.h>
#include <math.h>

namespace {
constexpr int Bb = 2;
constexpr int Ll = 2048;
constexpr int Dd = 1024;
constexpr int Hh = 16;
constexpr int NT = Bb * Ll;   // 4096 tokens
constexpr int D3 = 3 * Dd;    // 3072
constexpr int PH = Dd / 2;    // 512 phases per token
constexpr int LDK = 72;       // LDS row stride (bf16) for attn tiles
}

typedef __attribute__((ext_vector_type(8))) short bf16x8;
typedef __attribute__((ext_vector_type(4))) short bf16x4;
typedef __attribute__((ext_vector_type(4))) float f32x4;

#if defined(__has_builtin)
#if __has_builtin(__builtin_amdgcn_mfma_f32_16x16x16bf16_1k)
#define HAVE_MFMA16 1
#endif
#endif

__device__ inline unsigned pack2bf(float a, float b) {
  __hip_bfloat162 t = __float22bfloat162_rn(float2{a, b});
  union { __hip_bfloat162 h; unsigned u; } cv; cv.h = t;
  return cv.u;
}

__device__ inline bf16x4 u2bf4(uint2 u) {
  union { uint2 u; bf16x4 v; } c; c.u = u; return c.v;
}

// PV matmul piece: D = V^T-frag (A) x P-frag (B) + C at K=16 granularity.
__device__ inline f32x4 pv_mfma(bf16x4 va, bf16x4 vb, f32x4 c) {
#ifdef HAVE_MFMA16
  return __builtin_amdgcn_mfma_f32_16x16x16bf16_1k(va, vb, c, 0, 0, 0);
#else
  const bf16x8 a8 = {va[0], va[1], va[2], va[3], 0, 0, 0, 0};
  const bf16x8 b8 = {vb[0], vb[1], vb[2], vb[3], 0, 0, 0, 0};
  return __builtin_amdgcn_mfma_f32_16x16x32_bf16(a8, b8, c, 0, 0, 0);
#endif
}

__device__ inline void async_cp16(const void* gsrc, void* ldst) {
  __builtin_amdgcn_global_load_lds(
      (const __attribute__((address_space(1))) unsigned int*)gsrc,
      (__attribute__((address_space(3))) unsigned int*)ldst, 16, 0, 0);
}

// ---------------- merged input prep: split_cast(p) + trans_split(proj) + cast3 ------
// grid layout: [0,4096) split-cast p; [4096,4224) proj transpose+split;
//              [4224,12416) plain casts of x / W_qkv / W_out.
__global__ __launch_bounds__(256) void prep_kernel(
    const float4* __restrict__ p, uint2* __restrict__ p_hi4, uint2* __restrict__ p_lo4,
    const float* __restrict__ proj, short* __restrict__ th, short* __restrict__ tl,
    const float4* __restrict__ x, const float4* __restrict__ wq, const float4* __restrict__ wo,
    uint2* __restrict__ xd, uint2* __restrict__ wqd, uint2* __restrict__ wod)
{
  __shared__ float Ls[64][65];
  const int bid = blockIdx.x;
  const int tid = threadIdx.x;

  if (bid < 4096) {
    // hi/lo split cast of p
    const int i = bid * 256 + tid;
    const float4 f = p[i];
    float hf[4], lf[4];
    const float ff[4] = {f.x, f.y, f.z, f.w};
#pragma unroll
    for (int j = 0; j < 4; ++j) {
      const __hip_bfloat16 h = __float2bfloat16(ff[j]);
      hf[j] = __bfloat162float(h);
      lf[j] = ff[j] - hf[j];
    }
    p_hi4[i] = make_uint2(pack2bf(hf[0], hf[1]), pack2bf(hf[2], hf[3]));
    p_lo4[i] = make_uint2(pack2bf(lf[0], lf[1]), pack2bf(lf[2], lf[3]));
  } else if (bid < 4224) {
    // proj transpose + hi/lo split: [1024 d][512 m] -> [512 m][1024 d]
    const int bx = bid - 4096;
    const int d0 = (bx & 15) * 64, m0 = (bx >> 4) * 64;
    const int r = tid >> 4, c4 = (tid & 15) * 4;
#pragma unroll
    for (int it = 0; it < 4; ++it) {
      const int row = it * 16 + r;
      const float4 v = *(const float4*)&proj[(size_t)(d0 + row) * PH + m0 + c4];
      Ls[row][c4] = v.x; Ls[row][c4+1] = v.y; Ls[row][c4+2] = v.z; Ls[row][c4+3] = v.w;
    }
    __syncthreads();
#pragma unroll
    for (int it = 0; it < 4; ++it) {
      const int row = it * 16 + r;
      float hf[4], lf[4];
#pragma unroll
      for (int j = 0; j < 4; ++j) {
        const float v = Ls[c4 + j][row];
        const __hip_bfloat16 h = __float2bfloat16(v);
        hf[j] = __bfloat162float(h);
        lf[j] = v - hf[j];
      }
      *(uint2*)&th[(size_t)(m0 + row) * Dd + d0 + c4] = make_uint2(pack2bf(hf[0], hf[1]), pack2bf(hf[2], hf[3]));
      *(uint2*)&tl[(size_t)(m0 + row) * Dd + d0 + c4] = make_uint2(pack2bf(lf[0], lf[1]), pack2bf(lf[2], lf[3]));
    }
  } else {
    int i = (bid - 4224) * 256 + tid;   // covers 2,097,152
    const float4* s; uint2* d;
    if (i < 1048576) { s = x; d = xd; }
    else if (i < 1048576 + 786432) { i -= 1048576; s = wq; d = wqd; }
    else { i -= 1048576 + 786432; s = wo; d = wod; }
    const float4 f = s[i];
    d[i] = make_uint2(pack2bf(f.x, f.y), pack2bf(f.z, f.w));
  }
}

// ---------------- split-bf16 MFMA GEMM for phases: 128n x 64m tile ----------------
__global__ __launch_bounds__(256) void gemm_nn_split(
    const short* __restrict__ Ah_g, const short* __restrict__ Al_g,
    const short* __restrict__ Wh_g, const short* __restrict__ Wl_g,
    float* __restrict__ C)
{
  __shared__ __align__(16) short Ah[128 * 32], Al[128 * 32], Wh[64 * 32], Wl[64 * 32];
  const int tid = threadIdx.x;
  const int w = tid >> 6, lane = tid & 63;
  const int l15 = lane & 15, quad = lane >> 4;
  const int n0 = blockIdx.y * 128, m0 = blockIdx.x * 64;

  const int row = tid >> 2, cc = tid & 3;
  const int ksw = (cc ^ (row & 3)) * 8;
  const short* gAh = Ah_g + (size_t)(n0 + row) * Dd + ksw;
  const short* gAl = Al_g + (size_t)(n0 + row) * Dd + ksw;
  const short* gWh = Wh_g + (size_t)(m0 + row) * Dd + ksw;
  const short* gWl = Wl_g + (size_t)(m0 + row) * Dd + ksw;
  short* lAh  = Ah + tid * 8;
  short* lAh2 = Ah + 2048 + tid * 8;
  short* lAl  = Al + tid * 8;
  short* lAl2 = Al + 2048 + tid * 8;
  short* lWh  = Wh + tid * 8;
  short* lWl  = Wl + tid * 8;

  f32x4 acc[2][4];
#pragma unroll
  for (int i = 0; i < 2; ++i)
#pragma unroll
    for (int j = 0; j < 4; ++j) acc[i][j] = f32x4{0.f, 0.f, 0.f, 0.f};

  const int swq = (quad ^ (l15 & 3)) * 8;

  for (int k0 = 0; k0 < Dd; k0 += 32) {
    __syncthreads();
    async_cp16(gAh + k0, lAh);
    async_cp16(gAh + 64 * Dd + k0, lAh2);
    async_cp16(gAl + k0, lAl);
    async_cp16(gAl + 64 * Dd + k0, lAl2);
    async_cp16(gWh + k0, lWh);
    async_cp16(gWl + k0, lWl);
    __syncthreads();

    bf16x8 ah[2], al[2], wh[4], wl[4];
#pragma unroll
    for (int i = 0; i < 2; ++i) {
      ah[i] = *(const bf16x8*)&Ah[(w * 32 + i * 16 + l15) * 32 + swq];
      al[i] = *(const bf16x8*)&Al[(w * 32 + i * 16 + l15) * 32 + swq];
    }
#pragma unroll
    for (int j = 0; j < 4; ++j) {
      wh[j] = *(const bf16x8*)&Wh[(j * 16 + l15) * 32 + swq];
      wl[j] = *(const bf16x8*)&Wl[(j * 16 + l15) * 32 + swq];
    }
#pragma unroll
    for (int i = 0; i < 2; ++i)
#pragma unroll
      for (int j = 0; j < 4; ++j) {
        acc[i][j] = __builtin_amdgcn_mfma_f32_16x16x32_bf16(ah[i], wh[j], acc[i][j], 0, 0, 0);
        acc[i][j] = __builtin_amdgcn_mfma_f32_16x16x32_bf16(ah[i], wl[j], acc[i][j], 0, 0, 0);
        acc[i][j] = __builtin_amdgcn_mfma_f32_16x16x32_bf16(al[i], wh[j], acc[i][j], 0, 0, 0);
      }
  }

#pragma unroll
  for (int i = 0; i < 2; ++i)
#pragma unroll
    for (int r = 0; r < 4; ++r) {
      float* crow = C + (size_t)(n0 + w * 32 + i * 16 + quad * 4 + r) * PH + m0 + l15;
#pragma unroll
      for (int j = 0; j < 4; ++j) crow[j * 16] = acc[i][j][r];
    }
}

// ---------------- qkv GEMM with FUSED rotary/cast/V-transpose epilogue --------------
__global__ __launch_bounds__(256) void gemm_qkv_fused(
    const __hip_bfloat16* __restrict__ A, const __hip_bfloat16* __restrict__ W,
    const float* __restrict__ bias, const float* __restrict__ phases,
    __hip_bfloat16* __restrict__ q_bf, __hip_bfloat16* __restrict__ k_bf,
    __hip_bfloat16* __restrict__ vt_g)
{
  __shared__ __align__(16) short As[128 * 32];
  __shared__ __align__(16) short Ws[128 * 32];
  const int tid = threadIdx.x;
  const int w = tid >> 6, lane = tid & 63;
  const int l15 = lane & 15, quad = lane >> 4;
  const int wn = w >> 1, wm = w & 1;
  const int n0 = blockIdx.y * 128, m0 = blockIdx.x * 128;

  const int row = tid >> 2, cc = tid & 3;
  const int ksw = (cc ^ (row & 3)) * 8;
  const short* gA  = (const short*)A + (size_t)(n0 + row) * Dd + ksw;
  const short* gW  = (const short*)W + (size_t)(m0 + row) * Dd + ksw;
  short* lA  = As + tid * 8;
  short* lA2 = As + 2048 + tid * 8;
  short* lW  = Ws + tid * 8;
  short* lW2 = Ws + 2048 + tid * 8;

  f32x4 acc[4][4];
#pragma unroll
  for (int i = 0; i < 4; ++i)
#pragma unroll
    for (int j = 0; j < 4; ++j) acc[i][j] = f32x4{0.f, 0.f, 0.f, 0.f};

  const int swq = (quad ^ (l15 & 3)) * 8;

  for (int k0 = 0; k0 < Dd; k0 += 32) {
    __syncthreads();
    async_cp16(gA + k0, lA);
    async_cp16(gA + 64 * Dd + k0, lA2);
    async_cp16(gW + k0, lW);
    async_cp16(gW + 64 * Dd + k0, lW2);
    __syncthreads();

    bf16x8 af[4], bf[4];
#pragma unroll
    for (int i = 0; i < 4; ++i)
      af[i] = *(const bf16x8*)&As[(wn * 64 + i * 16 + l15) * 32 + swq];
#pragma unroll
    for (int j = 0; j < 4; ++j)
      bf[j] = *(const bf16x8*)&Ws[(wm * 64 + j * 16 + l15) * 32 + swq];
#pragma unroll
    for (int i = 0; i < 4; ++i)
#pragma unroll
      for (int j = 0; j < 4; ++j)
        acc[i][j] = __builtin_amdgcn_mfma_f32_16x16x32_bf16(af[i], bf[j], acc[i][j], 0, 0, 0);
  }

  float bv[4];
#pragma unroll
  for (int j = 0; j < 4; ++j) bv[j] = bias[m0 + wm * 64 + j * 16 + l15];

  const int region = m0 >> 10;                 // 0=q, 1=k, 2=v (block-uniform)
  const int mloc = (m0 & 1023) + wm * 64;
  const int h = mloc >> 6;

  if (region < 2) {
    __hip_bfloat16* dst = region == 0 ? q_bf : k_bf;
    const float SC = region == 0 ? 0.18033688011112042f : 1.0f;  // (1/8)*log2(e) on q
#pragma unroll
    for (int i = 0; i < 4; ++i)
#pragma unroll
      for (int r = 0; r < 4; ++r) {
        const int n = n0 + wn * 64 + i * 16 + quad * 4 + r;
        const float* phrow = phases + (size_t)n * PH + h * 32;
        __hip_bfloat16* drow = dst + (size_t)n * Dd + h * 64;
#pragma unroll
        for (int pz = 0; pz < 2; ++pz) {
          const float ph = phrow[pz * 16 + l15];
          float sn, cs;
          __sincosf(ph, &sn, &cs);
          const float a1 = acc[i][pz][r] + bv[pz];
          const float a2 = acc[i][pz + 2][r] + bv[pz + 2];
          drow[pz * 16 + l15]      = __float2bfloat16((a1 * cs - a2 * sn) * SC);
          drow[pz * 16 + 32 + l15] = __float2bfloat16((a1 * sn + a2 * cs) * SC);
        }
      }
  } else {
    const int bh = (n0 >> 11) * 16 + h;
    const int tokb = (n0 & 2047) + wn * 64;
#pragma unroll
    for (int i = 0; i < 4; ++i)
#pragma unroll
      for (int j = 0; j < 4; ++j) {
        const uint2 o = make_uint2(
            pack2bf(acc[i][j][0] + bv[j], acc[i][j][1] + bv[j]),
            pack2bf(acc[i][j][2] + bv[j], acc[i][j][3] + bv[j]));
        const int d = j * 16 + l15;
        *(uint2*)&vt_g[(size_t)(bh * 64 + d) * Ll + tokb + i * 16 + quad * 4] = o;
      }
  }
}

// ---------------- bf16 MFMA GEMM (out-proj):  C = bias + A @ W^T, fp32 out ----------
__global__ __launch_bounds__(256) void gemm_bt_bf16(
    const __hip_bfloat16* __restrict__ A, const __hip_bfloat16* __restrict__ W,
    const float* __restrict__ bias, float* __restrict__ C, int K, int M)
{
  __shared__ __align__(16) short As[128 * 32];
  __shared__ __align__(16) short Ws[128 * 32];
  const int tid = threadIdx.x;
  const int w = tid >> 6, lane = tid & 63;
  const int l15 = lane & 15, quad = lane >> 4;
  const int wn = w >> 1, wm = w & 1;
  const int n0 = blockIdx.y * 128, m0 = blockIdx.x * 128;

  const int row = tid >> 2, cc = tid & 3;
  const int ksw = (cc ^ (row & 3)) * 8;
  const short* gA  = (const short*)A + (size_t)(n0 + row) * K + ksw;
  const short* gW  = (const short*)W + (size_t)(m0 + row) * K + ksw;
  short* lA  = As + tid * 8;
  short* lA2 = As + 2048 + tid * 8;
  short* lW  = Ws + tid * 8;
  short* lW2 = Ws + 2048 + tid * 8;

  f32x4 acc[4][4];
#pragma unroll
  for (int i = 0; i < 4; ++i)
#pragma unroll
    for (int j = 0; j < 4; ++j) acc[i][j] = f32x4{0.f, 0.f, 0.f, 0.f};

  const int swq = (quad ^ (l15 & 3)) * 8;

  for (int k0 = 0; k0 < K; k0 += 32) {
    __syncthreads();
    async_cp16(gA + k0, lA);
    async_cp16(gA + 64 * K + k0, lA2);
    async_cp16(gW + k0, lW);
    async_cp16(gW + 64 * K + k0, lW2);
    __syncthreads();

    bf16x8 af[4], bf[4];
#pragma unroll
    for (int i = 0; i < 4; ++i)
      af[i] = *(const bf16x8*)&As[(wn * 64 + i * 16 + l15) * 32 + swq];
#pragma unroll
    for (int j = 0; j < 4; ++j)
      bf[j] = *(const bf16x8*)&Ws[(wm * 64 + j * 16 + l15) * 32 + swq];
#pragma unroll
    for (int i = 0; i < 4; ++i)
#pragma unroll
      for (int j = 0; j < 4; ++j)
        acc[i][j] = __builtin_amdgcn_mfma_f32_16x16x32_bf16(af[i], bf[j], acc[i][j], 0, 0, 0);
  }

  float bv[4];
#pragma unroll
  for (int j = 0; j < 4; ++j) bv[j] = bias[m0 + wm * 64 + j * 16 + l15];
#pragma unroll
  for (int i = 0; i < 4; ++i)
#pragma unroll
    for (int r = 0; r < 4; ++r) {
      float* crow = C + (size_t)(n0 + wn * 64 + i * 16 + quad * 4 + r) * M + m0 + wm * 64 + l15;
#pragma unroll
      for (int j = 0; j < 4; ++j) crow[j * 16] = acc[i][j][r] + bv[j];
    }
}

// ---------------- bf16 MFMA flash attention (double-buffered, 1 barrier/tile) -------
// Q-tile 128, K-tile 64. S^T = K·Q^T (exp2 domain, no online max). P packed by
// truncation; PV O^T = V^T·P at K=16 from registers; denominator via ones-row MFMA.
// LDS double-buffered: per tile: barrier -> store next tile -> issue loads for
// tile+2 -> compute current. Stores and global latency hide under compute.
__global__ __launch_bounds__(256) void attn_mfma(
    const __hip_bfloat16* __restrict__ q_bf,
    const __hip_bfloat16* __restrict__ k_bf,
    const __hip_bfloat16* __restrict__ vt_g,
    __hip_bfloat16* __restrict__ aout)
{
  __shared__ __align__(16) short Ks[2][64 * LDK];
  __shared__ __align__(16) short Vt[2][64 * LDK];

  const int tid = threadIdx.x;
  const int w = tid >> 6;
  const int lane = tid & 63;
  const int l15 = lane & 15;
  const int quad = lane >> 4;

  const int q0 = blockIdx.x * 128;
  const int bh = blockIdx.y;
  const int b = bh >> 4, h = bh & 15;

  bf16x8 qfrag[2][2];
#pragma unroll
  for (int qg = 0; qg < 2; ++qg)
#pragma unroll
    for (int kh = 0; kh < 2; ++kh) {
      const size_t qrow = (size_t)(b * Ll + q0 + w * 32 + qg * 16 + l15);
      qfrag[qg][kh] = *(const bf16x8*)(q_bf + qrow * Dd + h * 64 + kh * 32 + quad * 8);
    }

  f32x4 acc[4][2];
#pragma unroll
  for (int dt = 0; dt < 4; ++dt)
#pragma unroll
    for (int qg = 0; qg < 2; ++qg) acc[dt][qg] = f32x4{0.f, 0.f, 0.f, 0.f};
  f32x4 lden[2] = {f32x4{0.f,0.f,0.f,0.f}, f32x4{0.f,0.f,0.f,0.f}};
  const short one_bf = (short)0x3F80;           // bf16 1.0
  const bf16x4 ones = {one_bf, one_bf, one_bf, one_bf};

  const int srow = tid >> 2, sseg = tid & 3;
  const __hip_bfloat16* kbase = k_bf + (size_t)(b * Ll + srow) * Dd + h * 64 + sseg * 16;
  const __hip_bfloat16* vbase = vt_g + ((size_t)(bh * 64 + srow)) * Ll + sseg * 16;
  const int soff = srow * LDK + sseg * 16;

  uint4 pk0, pk1, pv0, pv1;
  // tile 0 -> regs -> buf0
  {
    const uint4* kg = (const uint4*)kbase;
    pk0 = kg[0]; pk1 = kg[1];
    const uint4* vg = (const uint4*)vbase;
    pv0 = vg[0]; pv1 = vg[1];
    *(uint4*)&Ks[0][soff]     = pk0;
    *(uint4*)&Ks[0][soff + 8] = pk1;
    *(uint4*)&Vt[0][soff]     = pv0;
    *(uint4*)&Vt[0][soff + 8] = pv1;
  }
  // tile 1 -> regs
  {
    const uint4* kg = (const uint4*)(kbase + (size_t)64 * Dd);
    pk0 = kg[0]; pk1 = kg[1];
    const uint4* vg = (const uint4*)(vbase + 64);
    pv0 = vg[0]; pv1 = vg[1];
  }

  for (int kt = 0; kt < Ll / 64; ++kt) {
    const int cur = kt & 1, nxt = cur ^ 1;
    __syncthreads();   // buf[cur] stores visible; buf[nxt] readers (tile kt-1) done
    // store tile kt+1 (regs) into buf[nxt]
    *(uint4*)&Ks[nxt][soff]     = pk0;
    *(uint4*)&Ks[nxt][soff + 8] = pk1;
    *(uint4*)&Vt[nxt][soff]     = pv0;
    *(uint4*)&Vt[nxt][soff + 8] = pv1;
    // issue global loads for tile kt+2 (hidden under compute)
    {
      const int ktn = (kt + 2) & 31;
      const uint4* kg = (const uint4*)(kbase + (size_t)ktn * 64 * Dd);
      pk0 = kg[0]; pk1 = kg[1];
      const uint4* vg = (const uint4*)(vbase + ktn * 64);
      pv0 = vg[0]; pv1 = vg[1];
    }

    f32x4 s[4][2];
#pragma unroll
    for (int n = 0; n < 4; ++n)
#pragma unroll
      for (int qg = 0; qg < 2; ++qg) s[n][qg] = f32x4{0.f, 0.f, 0.f, 0.f};
#pragma unroll
    for (int n = 0; n < 4; ++n)
#pragma unroll
      for (int kh = 0; kh < 2; ++kh) {
        const bf16x8 af = *(const bf16x8*)&Ks[cur][(n * 16 + l15) * LDK + kh * 32 + quad * 8];
        s[n][0] = __builtin_amdgcn_mfma_f32_16x16x32_bf16(af, qfrag[0][kh], s[n][0], 0, 0, 0);
        s[n][1] = __builtin_amdgcn_mfma_f32_16x16x32_bf16(af, qfrag[1][kh], s[n][1], 0, 0, 0);
      }

    // exp2 + truncation-pack (1 v_perm per pair)
    uint2 bq[4][2];
#pragma unroll
    for (int qg = 0; qg < 2; ++qg)
#pragma unroll
      for (int n = 0; n < 4; ++n) {
        union { float f; unsigned u; } p0, p1, p2, p3;
        p0.f = __builtin_amdgcn_exp2f(s[n][qg][0]);
        p1.f = __builtin_amdgcn_exp2f(s[n][qg][1]);
        p2.f = __builtin_amdgcn_exp2f(s[n][qg][2]);
        p3.f = __builtin_amdgcn_exp2f(s[n][qg][3]);
        bq[n][qg] = make_uint2(__builtin_amdgcn_perm(p1.u, p0.u, 0x07060302u),
                               __builtin_amdgcn_perm(p3.u, p2.u, 0x07060302u));
      }

    // O^T += V^T · P ; denominator += 1^T · P  (all in MFMA pipe)
#pragma unroll
    for (int n = 0; n < 4; ++n) {
      const bf16x4 pb0 = u2bf4(bq[n][0]);
      const bf16x4 pb1 = u2bf4(bq[n][1]);
      lden[0] = pv_mfma(ones, pb0, lden[0]);
      lden[1] = pv_mfma(ones, pb1, lden[1]);
#pragma unroll
      for (int dt = 0; dt < 4; ++dt) {
        const bf16x4 va = *(const bf16x4*)&Vt[cur][(dt * 16 + l15) * LDK + n * 16 + quad * 4];
        acc[dt][0] = pv_mfma(va, pb0, acc[dt][0]);
        acc[dt][1] = pv_mfma(va, pb1, acc[dt][1]);
      }
    }
  }

#pragma unroll
  for (int qg = 0; qg < 2; ++qg) {
    const float linv = 1.f / lden[qg][0];   // all rows identical; col l15 = this q
    const size_t q = (size_t)(b * Ll + q0 + w * 32 + qg * 16 + l15);
#pragma unroll
    for (int dt = 0; dt < 4; ++dt) {
      const uint2 o = make_uint2(
          pack2bf(acc[dt][qg][0] * linv, acc[dt][qg][1] * linv),
          pack2bf(acc[dt][qg][2] * linv, acc[dt][qg][3] * linv));
      *(uint2*)&aout[q * Dd + h * 64 + dt * 16 + quad * 4] = o;
    }
  }
}

extern "C" void kernel_launch(void* const* d_in, const int* in_sizes, int n_in,
                              void* d_out, int out_size, void* d_ws, size_t ws_size,
                              hipStream_t stream) {
  const float* x     = (const float*)d_in[0];
  const float* p     = (const float*)d_in[1];
  const float* W_qkv = (const float*)d_in[2];
  const float* b_qkv = (const float*)d_in[3];
  const float* W_out = (const float*)d_in[4];
  const float* b_out = (const float*)d_in[5];
  const float* proj  = (const float*)d_in[6];
  float* out = (float*)d_out;

  // workspace overlay (58 MiB used, < proven 72 MiB footprint):
  //  [0,8Mi):   phases fp32 (read by fused qkv epilogue)
  //  [8,16Mi):  p_hi  -> (dead after phases gemm) aout_bf
  //  [16,24Mi): p_lo  -> (dead after phases gemm) vt_g
  //  [24,25Mi): projt_hi   [25,26Mi): projt_lo
  //  [26,34Mi): q_bf   [34,42Mi): k_bf
  //  [42,50Mi): x_bf   [50,56Mi): wqkv_bf   [56,58Mi): wout_bf
  char* wsb = (char*)d_ws;
  float*          phases   = (float*)(wsb);
  short*          p_hi     = (short*)(wsb + (8u << 20));
  __hip_bfloat16* aout_bf  = (__hip_bfloat16*)(wsb + (8u << 20));
  short*          p_lo     = (short*)(wsb + (16u << 20));
  __hip_bfloat16* vt_g     = (__hip_bfloat16*)(wsb + (16u << 20));
  short*          projt_hi = (short*)(wsb + (24u << 20));
  short*          projt_lo = (short*)(wsb + (25u << 20));
  __hip_bfloat16* q_bf     = (__hip_bfloat16*)(wsb + (26u << 20));
  __hip_bfloat16* k_bf     = (__hip_bfloat16*)(wsb + (34u << 20));
  __hip_bfloat16* x_bf     = (__hip_bfloat16*)(wsb + (42u << 20));
  __hip_bfloat16* wqkv_bf  = (__hip_bfloat16*)(wsb + (50u << 20));
  __hip_bfloat16* wout_bf  = (__hip_bfloat16*)(wsb + (56u << 20));

  // merged input prep (split-cast p, transpose+split proj, cast x/W_qkv/W_out)
  prep_kernel<<<12416, 256, 0, stream>>>(
      (const float4*)p, (uint2*)p_hi, (uint2*)p_lo,
      proj, projt_hi, projt_lo,
      (const float4*)x, (const float4*)W_qkv, (const float4*)W_out,
      (uint2*)x_bf, (uint2*)wqkv_bf, (uint2*)wout_bf);
  // phases = p @ proj (split-bf16, 128x64 tiles)
  gemm_nn_split<<<dim3(PH / 64, NT / 128), 256, 0, stream>>>(p_hi, p_lo, projt_hi, projt_lo, phases);
  // qkv GEMM + fused rotary/cast/V-transpose epilogue
  gemm_qkv_fused<<<dim3(D3 / 128, NT / 128), 256, 0, stream>>>(x_bf, wqkv_bf, b_qkv, phases,
                                                               q_bf, k_bf, vt_g);
  // flash attention -> aout bf16
  attn_mfma<<<dim3(Ll / 128, Bb * Hh), 256, 0, stream>>>(q_bf, k_bf, vt_g, aout_bf);
  // out = aout @ W_out^T + b_out
  gemm_bt_bf16<<<dim3(Dd / 128, NT / 128), 256, 0, stream>>>(aout_bf, wout_bf, b_out, out, Dd, Dd);
}

// Round 9
// 262.696 us; speedup vs baseline: 1.0305x; 1.0305x over previous
//
#include <hip/hip_runtime.h>
#include <hip/hip_bf16.h>
#include <math.h>

namespace {
constexpr int Bb = 2;
constexpr int Ll = 2048;
constexpr int Dd = 1024;
constexpr int Hh = 16;
constexpr int NT = Bb * Ll;   // 4096 tokens
constexpr int D3 = 3 * Dd;    // 3072
constexpr int PH = Dd / 2;    // 512 phases per token
constexpr int LDK = 72;       // LDS row stride (bf16) for attn tiles
}

typedef __attribute__((ext_vector_type(8))) short bf16x8;
typedef __attribute__((ext_vector_type(4))) short bf16x4;
typedef __attribute__((ext_vector_type(4))) float f32x4;

#if defined(__has_builtin)
#if __has_builtin(__builtin_amdgcn_mfma_f32_16x16x16bf16_1k)
#define HAVE_MFMA16 1
#endif
#endif

__device__ inline unsigned pack2bf(float a, float b) {
  __hip_bfloat162 t = __float22bfloat162_rn(float2{a, b});
  union { __hip_bfloat162 h; unsigned u; } cv; cv.h = t;
  return cv.u;
}

__device__ inline bf16x4 u2bf4(uint2 u) {
  union { uint2 u; bf16x4 v; } c; c.u = u; return c.v;
}

__device__ inline float bfhalf(unsigned u, int hi) {
  union { unsigned u; float f; } c;
  c.u = hi ? (u & 0xffff0000u) : (u << 16);
  return c.f;
}

// PV matmul piece: D = V^T-frag (A) x P-frag (B) + C at K=16 granularity.
__device__ inline f32x4 pv_mfma(bf16x4 va, bf16x4 vb, f32x4 c) {
#ifdef HAVE_MFMA16
  return __builtin_amdgcn_mfma_f32_16x16x16bf16_1k(va, vb, c, 0, 0, 0);
#else
  const bf16x8 a8 = {va[0], va[1], va[2], va[3], 0, 0, 0, 0};
  const bf16x8 b8 = {vb[0], vb[1], vb[2], vb[3], 0, 0, 0, 0};
  return __builtin_amdgcn_mfma_f32_16x16x32_bf16(a8, b8, c, 0, 0, 0);
#endif
}

__device__ inline void async_cp16(const void* gsrc, void* ldst) {
  __builtin_amdgcn_global_load_lds(
      (const __attribute__((address_space(1))) unsigned int*)gsrc,
      (__attribute__((address_space(3))) unsigned int*)ldst, 16, 0, 0);
}

// ---------------- merged input prep: split_cast(p) + trans_split(proj) + cast3 ------
__global__ __launch_bounds__(256) void prep_kernel(
    const float4* __restrict__ p, uint2* __restrict__ p_hi4, uint2* __restrict__ p_lo4,
    const float* __restrict__ proj, short* __restrict__ th, short* __restrict__ tl,
    const float4* __restrict__ x, const float4* __restrict__ wq, const float4* __restrict__ wo,
    uint2* __restrict__ xd, uint2* __restrict__ wqd, uint2* __restrict__ wod)
{
  __shared__ float Ls[64][65];
  const int bid = blockIdx.x;
  const int tid = threadIdx.x;

  if (bid < 4096) {
    const int i = bid * 256 + tid;
    const float4 f = p[i];
    float hf[4], lf[4];
    const float ff[4] = {f.x, f.y, f.z, f.w};
#pragma unroll
    for (int j = 0; j < 4; ++j) {
      const __hip_bfloat16 h = __float2bfloat16(ff[j]);
      hf[j] = __bfloat162float(h);
      lf[j] = ff[j] - hf[j];
    }
    p_hi4[i] = make_uint2(pack2bf(hf[0], hf[1]), pack2bf(hf[2], hf[3]));
    p_lo4[i] = make_uint2(pack2bf(lf[0], lf[1]), pack2bf(lf[2], lf[3]));
  } else if (bid < 4224) {
    const int bx = bid - 4096;
    const int d0 = (bx & 15) * 64, m0 = (bx >> 4) * 64;
    const int r = tid >> 4, c4 = (tid & 15) * 4;
#pragma unroll
    for (int it = 0; it < 4; ++it) {
      const int row = it * 16 + r;
      const float4 v = *(const float4*)&proj[(size_t)(d0 + row) * PH + m0 + c4];
      Ls[row][c4] = v.x; Ls[row][c4+1] = v.y; Ls[row][c4+2] = v.z; Ls[row][c4+3] = v.w;
    }
    __syncthreads();
#pragma unroll
    for (int it = 0; it < 4; ++it) {
      const int row = it * 16 + r;
      float hf[4], lf[4];
#pragma unroll
      for (int j = 0; j < 4; ++j) {
        const float v = Ls[c4 + j][row];
        const __hip_bfloat16 h = __float2bfloat16(v);
        hf[j] = __bfloat162float(h);
        lf[j] = v - hf[j];
      }
      *(uint2*)&th[(size_t)(m0 + row) * Dd + d0 + c4] = make_uint2(pack2bf(hf[0], hf[1]), pack2bf(hf[2], hf[3]));
      *(uint2*)&tl[(size_t)(m0 + row) * Dd + d0 + c4] = make_uint2(pack2bf(lf[0], lf[1]), pack2bf(lf[2], lf[3]));
    }
  } else {
    int i = (bid - 4224) * 256 + tid;   // covers 2,097,152
    const float4* s; uint2* d;
    if (i < 1048576) { s = x; d = xd; }
    else if (i < 1048576 + 786432) { i -= 1048576; s = wq; d = wqd; }
    else { i -= 1048576 + 786432; s = wo; d = wod; }
    const float4 f = s[i];
    d[i] = make_uint2(pack2bf(f.x, f.y), pack2bf(f.z, f.w));
  }
}

// ---------------- split-bf16 MFMA GEMM for phases: 128n x 64m tile ----------------
__global__ __launch_bounds__(256) void gemm_nn_split(
    const short* __restrict__ Ah_g, const short* __restrict__ Al_g,
    const short* __restrict__ Wh_g, const short* __restrict__ Wl_g,
    float* __restrict__ C)
{
  __shared__ __align__(16) short Ah[128 * 32], Al[128 * 32], Wh[64 * 32], Wl[64 * 32];
  const int tid = threadIdx.x;
  const int w = tid >> 6, lane = tid & 63;
  const int l15 = lane & 15, quad = lane >> 4;
  const int n0 = blockIdx.y * 128, m0 = blockIdx.x * 64;

  const int row = tid >> 2, cc = tid & 3;
  const int ksw = (cc ^ (row & 3)) * 8;
  const short* gAh = Ah_g + (size_t)(n0 + row) * Dd + ksw;
  const short* gAl = Al_g + (size_t)(n0 + row) * Dd + ksw;
  const short* gWh = Wh_g + (size_t)(m0 + row) * Dd + ksw;
  const short* gWl = Wl_g + (size_t)(m0 + row) * Dd + ksw;
  short* lAh  = Ah + tid * 8;
  short* lAh2 = Ah + 2048 + tid * 8;
  short* lAl  = Al + tid * 8;
  short* lAl2 = Al + 2048 + tid * 8;
  short* lWh  = Wh + tid * 8;
  short* lWl  = Wl + tid * 8;

  f32x4 acc[2][4];
#pragma unroll
  for (int i = 0; i < 2; ++i)
#pragma unroll
    for (int j = 0; j < 4; ++j) acc[i][j] = f32x4{0.f, 0.f, 0.f, 0.f};

  const int swq = (quad ^ (l15 & 3)) * 8;

  for (int k0 = 0; k0 < Dd; k0 += 32) {
    __syncthreads();
    async_cp16(gAh + k0, lAh);
    async_cp16(gAh + 64 * Dd + k0, lAh2);
    async_cp16(gAl + k0, lAl);
    async_cp16(gAl + 64 * Dd + k0, lAl2);
    async_cp16(gWh + k0, lWh);
    async_cp16(gWl + k0, lWl);
    __syncthreads();

    bf16x8 ah[2], al[2], wh[4], wl[4];
#pragma unroll
    for (int i = 0; i < 2; ++i) {
      ah[i] = *(const bf16x8*)&Ah[(w * 32 + i * 16 + l15) * 32 + swq];
      al[i] = *(const bf16x8*)&Al[(w * 32 + i * 16 + l15) * 32 + swq];
    }
#pragma unroll
    for (int j = 0; j < 4; ++j) {
      wh[j] = *(const bf16x8*)&Wh[(j * 16 + l15) * 32 + swq];
      wl[j] = *(const bf16x8*)&Wl[(j * 16 + l15) * 32 + swq];
    }
#pragma unroll
    for (int i = 0; i < 2; ++i)
#pragma unroll
      for (int j = 0; j < 4; ++j) {
        acc[i][j] = __builtin_amdgcn_mfma_f32_16x16x32_bf16(ah[i], wh[j], acc[i][j], 0, 0, 0);
        acc[i][j] = __builtin_amdgcn_mfma_f32_16x16x32_bf16(ah[i], wl[j], acc[i][j], 0, 0, 0);
        acc[i][j] = __builtin_amdgcn_mfma_f32_16x16x32_bf16(al[i], wh[j], acc[i][j], 0, 0, 0);
      }
  }

#pragma unroll
  for (int i = 0; i < 2; ++i)
#pragma unroll
    for (int r = 0; r < 4; ++r) {
      float* crow = C + (size_t)(n0 + w * 32 + i * 16 + quad * 4 + r) * PH + m0 + l15;
#pragma unroll
      for (int j = 0; j < 4; ++j) crow[j * 16] = acc[i][j][r];
    }
}

// ---------------- qkv GEMM with FUSED rotary/cast/V-transpose epilogue --------------
__global__ __launch_bounds__(256) void gemm_qkv_fused(
    const __hip_bfloat16* __restrict__ A, const __hip_bfloat16* __restrict__ W,
    const float* __restrict__ bias, const float* __restrict__ phases,
    __hip_bfloat16* __restrict__ q_bf, __hip_bfloat16* __restrict__ k_bf,
    __hip_bfloat16* __restrict__ vt_g)
{
  __shared__ __align__(16) short As[128 * 32];
  __shared__ __align__(16) short Ws[128 * 32];
  const int tid = threadIdx.x;
  const int w = tid >> 6, lane = tid & 63;
  const int l15 = lane & 15, quad = lane >> 4;
  const int wn = w >> 1, wm = w & 1;
  const int n0 = blockIdx.y * 128, m0 = blockIdx.x * 128;

  const int row = tid >> 2, cc = tid & 3;
  const int ksw = (cc ^ (row & 3)) * 8;
  const short* gA  = (const short*)A + (size_t)(n0 + row) * Dd + ksw;
  const short* gW  = (const short*)W + (size_t)(m0 + row) * Dd + ksw;
  short* lA  = As + tid * 8;
  short* lA2 = As + 2048 + tid * 8;
  short* lW  = Ws + tid * 8;
  short* lW2 = Ws + 2048 + tid * 8;

  f32x4 acc[4][4];
#pragma unroll
  for (int i = 0; i < 4; ++i)
#pragma unroll
    for (int j = 0; j < 4; ++j) acc[i][j] = f32x4{0.f, 0.f, 0.f, 0.f};

  const int swq = (quad ^ (l15 & 3)) * 8;

  for (int k0 = 0; k0 < Dd; k0 += 32) {
    __syncthreads();
    async_cp16(gA + k0, lA);
    async_cp16(gA + 64 * Dd + k0, lA2);
    async_cp16(gW + k0, lW);
    async_cp16(gW + 64 * Dd + k0, lW2);
    __syncthreads();

    bf16x8 af[4], bf[4];
#pragma unroll
    for (int i = 0; i < 4; ++i)
      af[i] = *(const bf16x8*)&As[(wn * 64 + i * 16 + l15) * 32 + swq];
#pragma unroll
    for (int j = 0; j < 4; ++j)
      bf[j] = *(const bf16x8*)&Ws[(wm * 64 + j * 16 + l15) * 32 + swq];
#pragma unroll
    for (int i = 0; i < 4; ++i)
#pragma unroll
      for (int j = 0; j < 4; ++j)
        acc[i][j] = __builtin_amdgcn_mfma_f32_16x16x32_bf16(af[i], bf[j], acc[i][j], 0, 0, 0);
  }

  float bv[4];
#pragma unroll
  for (int j = 0; j < 4; ++j) bv[j] = bias[m0 + wm * 64 + j * 16 + l15];

  const int region = m0 >> 10;                 // 0=q, 1=k, 2=v (block-uniform)
  const int mloc = (m0 & 1023) + wm * 64;
  const int h = mloc >> 6;

  if (region < 2) {
    __hip_bfloat16* dst = region == 0 ? q_bf : k_bf;
    const float SC = region == 0 ? 0.18033688011112042f : 1.0f;  // (1/8)*log2(e) on q
#pragma unroll
    for (int i = 0; i < 4; ++i)
#pragma unroll
      for (int r = 0; r < 4; ++r) {
        const int n = n0 + wn * 64 + i * 16 + quad * 4 + r;
        const float* phrow = phases + (size_t)n * PH + h * 32;
        __hip_bfloat16* drow = dst + (size_t)n * Dd + h * 64;
#pragma unroll
        for (int pz = 0; pz < 2; ++pz) {
          const float ph = phrow[pz * 16 + l15];
          float sn, cs;
          __sincosf(ph, &sn, &cs);
          const float a1 = acc[i][pz][r] + bv[pz];
          const float a2 = acc[i][pz + 2][r] + bv[pz + 2];
          drow[pz * 16 + l15]      = __float2bfloat16((a1 * cs - a2 * sn) * SC);
          drow[pz * 16 + 32 + l15] = __float2bfloat16((a1 * sn + a2 * cs) * SC);
        }
      }
  } else {
    const int bh = (n0 >> 11) * 16 + h;
    const int tokb = (n0 & 2047) + wn * 64;
#pragma unroll
    for (int i = 0; i < 4; ++i)
#pragma unroll
      for (int j = 0; j < 4; ++j) {
        const uint2 o = make_uint2(
            pack2bf(acc[i][j][0] + bv[j], acc[i][j][1] + bv[j]),
            pack2bf(acc[i][j][2] + bv[j], acc[i][j][3] + bv[j]));
        const int d = j * 16 + l15;
        *(uint2*)&vt_g[(size_t)(bh * 64 + d) * Ll + tokb + i * 16 + quad * 4] = o;
      }
  }
}

// ---------------- out-proj GEMM: 128n x 64m tile (512 blocks, 2/CU) -----------------
__global__ __launch_bounds__(256) void gemm_bt_64(
    const __hip_bfloat16* __restrict__ A, const __hip_bfloat16* __restrict__ W,
    const float* __restrict__ bias, float* __restrict__ C, int K, int M)
{
  __shared__ __align__(16) short As[128 * 32];
  __shared__ __align__(16) short Ws[64 * 32];
  const int tid = threadIdx.x;
  const int w = tid >> 6, lane = tid & 63;
  const int l15 = lane & 15, quad = lane >> 4;
  const int n0 = blockIdx.y * 128, m0 = blockIdx.x * 64;

  const int row = tid >> 2, cc = tid & 3;
  const int ksw = (cc ^ (row & 3)) * 8;
  const short* gA = (const short*)A + (size_t)(n0 + row) * K + ksw;
  const short* gW = (const short*)W + (size_t)(m0 + row) * K + ksw;
  short* lA  = As + tid * 8;
  short* lA2 = As + 2048 + tid * 8;
  short* lW  = Ws + tid * 8;

  f32x4 acc[2][4];
#pragma unroll
  for (int i = 0; i < 2; ++i)
#pragma unroll
    for (int j = 0; j < 4; ++j) acc[i][j] = f32x4{0.f, 0.f, 0.f, 0.f};

  const int swq = (quad ^ (l15 & 3)) * 8;

  for (int k0 = 0; k0 < K; k0 += 32) {
    __syncthreads();
    async_cp16(gA + k0, lA);
    async_cp16(gA + 64 * K + k0, lA2);
    async_cp16(gW + k0, lW);
    __syncthreads();

    bf16x8 af[2], bf[4];
#pragma unroll
    for (int i = 0; i < 2; ++i)
      af[i] = *(const bf16x8*)&As[(w * 32 + i * 16 + l15) * 32 + swq];
#pragma unroll
    for (int j = 0; j < 4; ++j)
      bf[j] = *(const bf16x8*)&Ws[(j * 16 + l15) * 32 + swq];
#pragma unroll
    for (int i = 0; i < 2; ++i)
#pragma unroll
      for (int j = 0; j < 4; ++j)
        acc[i][j] = __builtin_amdgcn_mfma_f32_16x16x32_bf16(af[i], bf[j], acc[i][j], 0, 0, 0);
  }

  float bv[4];
#pragma unroll
  for (int j = 0; j < 4; ++j) bv[j] = bias[m0 + j * 16 + l15];
#pragma unroll
  for (int i = 0; i < 2; ++i)
#pragma unroll
    for (int r = 0; r < 4; ++r) {
      float* crow = C + (size_t)(n0 + w * 32 + i * 16 + quad * 4 + r) * M + m0 + l15;
#pragma unroll
      for (int j = 0; j < 4; ++j) crow[j * 16] = acc[i][j][r] + bv[j];
    }
}

// ---------------- bf16 MFMA flash attention (split-K, R7 loop structure) ------------
// Q-tile 128, K-tile 64, blockIdx.z selects kt half [z*16, z*16+16). Grid 1024
// blocks = 4/CU. exp2-domain (no max) makes partials additive: each block writes
// its own-normalized O (bf16) and denominator (fp32); combine kernel merges.
__global__ __launch_bounds__(256) void attn_mfma(
    const __hip_bfloat16* __restrict__ q_bf,
    const __hip_bfloat16* __restrict__ k_bf,
    const __hip_bfloat16* __restrict__ vt_g,
    __hip_bfloat16* __restrict__ o_part,   // [2][NT][Dd] bf16
    float* __restrict__ lden_g)            // [2][Bb][Hh][Ll] fp32
{
  __shared__ __align__(16) short Ks[64 * LDK];
  __shared__ __align__(16) short Vt[64 * LDK];

  const int tid = threadIdx.x;
  const int w = tid >> 6;
  const int lane = tid & 63;
  const int l15 = lane & 15;
  const int quad = lane >> 4;

  const int q0 = blockIdx.x * 128;
  const int bh = blockIdx.y;
  const int kz = blockIdx.z;
  const int b = bh >> 4, h = bh & 15;
  const int kt0 = kz * 16;

  bf16x8 qfrag[2][2];
#pragma unroll
  for (int qg = 0; qg < 2; ++qg)
#pragma unroll
    for (int kh = 0; kh < 2; ++kh) {
      const size_t qrow = (size_t)(b * Ll + q0 + w * 32 + qg * 16 + l15);
      qfrag[qg][kh] = *(const bf16x8*)(q_bf + qrow * Dd + h * 64 + kh * 32 + quad * 8);
    }

  f32x4 acc[4][2];
#pragma unroll
  for (int dt = 0; dt < 4; ++dt)
#pragma unroll
    for (int qg = 0; qg < 2; ++qg) acc[dt][qg] = f32x4{0.f, 0.f, 0.f, 0.f};
  f32x4 lden[2] = {f32x4{0.f,0.f,0.f,0.f}, f32x4{0.f,0.f,0.f,0.f}};
  const short one_bf = (short)0x3F80;           // bf16 1.0
  const bf16x4 ones = {one_bf, one_bf, one_bf, one_bf};

  const int srow = tid >> 2, sseg = tid & 3;
  const __hip_bfloat16* kbase = k_bf + (size_t)(b * Ll + srow) * Dd + h * 64 + sseg * 16;
  const __hip_bfloat16* vbase = vt_g + ((size_t)(bh * 64 + srow)) * Ll + sseg * 16;

  // prefetch first tile of this half into registers
  uint4 pk0, pk1, pv0, pv1;
  {
    const uint4* kg = (const uint4*)(kbase + (size_t)kt0 * 64 * Dd);
    pk0 = kg[0]; pk1 = kg[1];
    const uint4* vg = (const uint4*)(vbase + kt0 * 64);
    pv0 = vg[0]; pv1 = vg[1];
  }

  for (int kt = 0; kt < 16; ++kt) {
    __syncthreads();   // previous tile's LDS reads complete
    *(uint4*)&Ks[srow * LDK + sseg * 16]     = pk0;
    *(uint4*)&Ks[srow * LDK + sseg * 16 + 8] = pk1;
    *(uint4*)&Vt[srow * LDK + sseg * 16]     = pv0;
    *(uint4*)&Vt[srow * LDK + sseg * 16 + 8] = pv1;
    __syncthreads();

    // issue next tile's global loads (overlap with compute below)
    {
      const int ktn = kt0 + ((kt + 1) & 15);
      const uint4* kg = (const uint4*)(kbase + (size_t)ktn * 64 * Dd);
      pk0 = kg[0]; pk1 = kg[1];
      const uint4* vg = (const uint4*)(vbase + ktn * 64);
      pv0 = vg[0]; pv1 = vg[1];
    }

    f32x4 s[4][2];
#pragma unroll
    for (int n = 0; n < 4; ++n)
#pragma unroll
      for (int qg = 0; qg < 2; ++qg) s[n][qg] = f32x4{0.f, 0.f, 0.f, 0.f};
#pragma unroll
    for (int n = 0; n < 4; ++n)
#pragma unroll
      for (int kh = 0; kh < 2; ++kh) {
        const bf16x8 af = *(const bf16x8*)&Ks[(n * 16 + l15) * LDK + kh * 32 + quad * 8];
        s[n][0] = __builtin_amdgcn_mfma_f32_16x16x32_bf16(af, qfrag[0][kh], s[n][0], 0, 0, 0);
        s[n][1] = __builtin_amdgcn_mfma_f32_16x16x32_bf16(af, qfrag[1][kh], s[n][1], 0, 0, 0);
      }

    // exp2 + truncation-pack (1 v_perm per pair)
    uint2 bq[4][2];
#pragma unroll
    for (int qg = 0; qg < 2; ++qg)
#pragma unroll
      for (int n = 0; n < 4; ++n) {
        union { float f; unsigned u; } p0, p1, p2, p3;
        p0.f = __builtin_amdgcn_exp2f(s[n][qg][0]);
        p1.f = __builtin_amdgcn_exp2f(s[n][qg][1]);
        p2.f = __builtin_amdgcn_exp2f(s[n][qg][2]);
        p3.f = __builtin_amdgcn_exp2f(s[n][qg][3]);
        bq[n][qg] = make_uint2(__builtin_amdgcn_perm(p1.u, p0.u, 0x07060302u),
                               __builtin_amdgcn_perm(p3.u, p2.u, 0x07060302u));
      }

    // O^T += V^T · P ; denominator += 1^T · P  (all in MFMA pipe)
#pragma unroll
    for (int n = 0; n < 4; ++n) {
      const bf16x4 pb0 = u2bf4(bq[n][0]);
      const bf16x4 pb1 = u2bf4(bq[n][1]);
      lden[0] = pv_mfma(ones, pb0, lden[0]);
      lden[1] = pv_mfma(ones, pb1, lden[1]);
#pragma unroll
      for (int dt = 0; dt < 4; ++dt) {
        const bf16x4 va = *(const bf16x4*)&Vt[(dt * 16 + l15) * LDK + n * 16 + quad * 4];
        acc[dt][0] = pv_mfma(va, pb0, acc[dt][0]);
        acc[dt][1] = pv_mfma(va, pb1, acc[dt][1]);
      }
    }
  }

#pragma unroll
  for (int qg = 0; qg < 2; ++qg) {
    const float lv = lden[qg][0];           // all rows identical; col l15 = this q
    const float linv = 1.f / lv;
    const int ql = q0 + w * 32 + qg * 16 + l15;
    if (quad == 0)
      lden_g[((size_t)(kz * Bb + b) * Hh + h) * Ll + ql] = lv;
    __hip_bfloat16* dst = o_part + ((size_t)kz * NT + b * Ll + ql) * Dd + h * 64;
#pragma unroll
    for (int dt = 0; dt < 4; ++dt) {
      const uint2 o = make_uint2(
          pack2bf(acc[dt][qg][0] * linv, acc[dt][qg][1] * linv),
          pack2bf(acc[dt][qg][2] * linv, acc[dt][qg][3] * linv));
      *(uint2*)&dst[dt * 16 + quad * 4] = o;
    }
  }
}

// ---------------- combine the two split-K partials -----------------------------------
// aout[n][d] = (l0*O0 + l1*O1) / (l0+l1); one thread per 4 d.
__global__ __launch_bounds__(256) void attn_combine(
    const __hip_bfloat16* __restrict__ o_part, const float* __restrict__ lden_g,
    __hip_bfloat16* __restrict__ aout)
{
  const int i = blockIdx.x * 256 + threadIdx.x;   // NT*Dd/4 = 1,048,576
  const int n = i >> 8, d4 = i & 255;
  const int b = n >> 11, l = n & 2047;
  const int h = d4 >> 4;
  const float l0 = lden_g[((size_t)b * Hh + h) * Ll + l];
  const float l1 = lden_g[((size_t)(Bb + b) * Hh + h) * Ll + l];
  const float inv = 1.f / (l0 + l1);
  const float w0 = l0 * inv, w1 = l1 * inv;
  const uint2 a0 = ((const uint2*)o_part)[i];
  const uint2 a1 = ((const uint2*)o_part)[(NT * (size_t)Dd / 4) + i];
  const float r0 = w0 * bfhalf(a0.x, 0) + w1 * bfhalf(a1.x, 0);
  const float r1 = w0 * bfhalf(a0.x, 1) + w1 * bfhalf(a1.x, 1);
  const float r2 = w0 * bfhalf(a0.y, 0) + w1 * bfhalf(a1.y, 0);
  const float r3 = w0 * bfhalf(a0.y, 1) + w1 * bfhalf(a1.y, 1);
  ((uint2*)aout)[i] = make_uint2(pack2bf(r0, r1), pack2bf(r2, r3));
}

extern "C" void kernel_launch(void* const* d_in, const int* in_sizes, int n_in,
                              void* d_out, int out_size, void* d_ws, size_t ws_size,
                              hipStream_t stream) {
  const float* x     = (const float*)d_in[0];
  const float* p     = (const float*)d_in[1];
  const float* W_qkv = (const float*)d_in[2];
  const float* b_qkv = (const float*)d_in[3];
  const float* W_out = (const float*)d_in[4];
  const float* b_out = (const float*)d_in[5];
  const float* proj  = (const float*)d_in[6];
  float* out = (float*)d_out;

  // workspace overlay (~61 MiB, < proven 72 MiB footprint):
  //  [0,8Mi):   phases fp32
  //  [8,16Mi):  p_hi  -> (dead after phases gemm) aout_bf
  //  [16,24Mi): p_lo  -> (dead after phases gemm) vt_g
  //  [24,25Mi): projt_hi   [25,26Mi): projt_lo
  //  [26,34Mi): q_bf   [34,42Mi): k_bf
  //  [42,50Mi): x_bf     -> (dead after qkv gemm) o_part z0
  //  [50,56Mi): wqkv_bf  -> (dead after qkv gemm) o_part z1 [50,58Mi)
  //  [58,60Mi): wout_bf
  //  [60,60.5Mi): lden_g
  char* wsb = (char*)d_ws;
  float*          phases   = (float*)(wsb);
  short*          p_hi     = (short*)(wsb + (8u << 20));
  __hip_bfloat16* aout_bf  = (__hip_bfloat16*)(wsb + (8u << 20));
  short*          p_lo     = (short*)(wsb + (16u << 20));
  __hip_bfloat16* vt_g     = (__hip_bfloat16*)(wsb + (16u << 20));
  short*          projt_hi = (short*)(wsb + (24u << 20));
  short*          projt_lo = (short*)(wsb + (25u << 20));
  __hip_bfloat16* q_bf     = (__hip_bfloat16*)(wsb + (26u << 20));
  __hip_bfloat16* k_bf     = (__hip_bfloat16*)(wsb + (34u << 20));
  __hip_bfloat16* x_bf     = (__hip_bfloat16*)(wsb + (42u << 20));
  __hip_bfloat16* o_part   = (__hip_bfloat16*)(wsb + (42u << 20));
  __hip_bfloat16* wqkv_bf  = (__hip_bfloat16*)(wsb + (50u << 20));
  __hip_bfloat16* wout_bf  = (__hip_bfloat16*)(wsb + (58u << 20));
  float*          lden_g   = (float*)(wsb + (60u << 20));

  // merged input prep
  prep_kernel<<<12416, 256, 0, stream>>>(
      (const float4*)p, (uint2*)p_hi, (uint2*)p_lo,
      proj, projt_hi, projt_lo,
      (const float4*)x, (const float4*)W_qkv, (const float4*)W_out,
      (uint2*)x_bf, (uint2*)wqkv_bf, (uint2*)wout_bf);
  // phases = p @ proj (split-bf16)
  gemm_nn_split<<<dim3(PH / 64, NT / 128), 256, 0, stream>>>(p_hi, p_lo, projt_hi, projt_lo, phases);
  // qkv GEMM + fused rotary/cast/V-transpose epilogue
  gemm_qkv_fused<<<dim3(D3 / 128, NT / 128), 256, 0, stream>>>(x_bf, wqkv_bf, b_qkv, phases,
                                                               q_bf, k_bf, vt_g);
  // flash attention (split-K halves) -> partials
  attn_mfma<<<dim3(Ll / 128, Bb * Hh, 2), 256, 0, stream>>>(q_bf, k_bf, vt_g, o_part, lden_g);
  // combine partials -> aout bf16
  attn_combine<<<4096, 256, 0, stream>>>(o_part, lden_g, aout_bf);
  // out = aout @ W_out^T + b_out (128n x 64m tiles, 512 blocks)
  gemm_bt_64<<<dim3(Dd / 64, NT / 128), 256, 0, stream>>>(aout_bf, wout_bf, b_out, out, Dd, Dd);
}